// Round 9
// baseline (78.192 us; speedup 1.0000x reference)
//
#include <hip/hip_runtime.h>
#include <math.h>

#define DIMV 512
#define LTOK 64
#define SEG  512      // N_PATCH / L_TOK
#define NWIN 16
#define WSZ  64
#define NB   8        // 96-row tiles per segment (stride 64): windows (2c, 2c+1)
#define INV_SQRT_D 0.044194173824159216f   // 1/sqrt(512)

__device__ __forceinline__ float wave_sum(float v) {
#pragma unroll
  for (int m = 1; m < 64; m <<= 1) v += __shfl_xor(v, m, 64);
  return v;
}
__device__ __forceinline__ float wave_max(float v) {
#pragma unroll
  for (int m = 1; m < 64; m <<= 1) v = fmaxf(v, __shfl_xor(v, m, 64));
  return v;
}

// q[l][d] = z_l . Wq_d (1024 blocks: 64 l x 16 chunks; 256 thr).
// Side task: wave 0 computes window (l, c)'s coordinate mean.
__global__ __launch_bounds__(256, 4) void k_q(const float* __restrict__ z,
    const float* __restrict__ Wq, const float* __restrict__ coords,
    float* __restrict__ q, float* __restrict__ cmean)
{
  int l = blockIdx.x >> 4, c = blockIdx.x & 15;
  int wave = threadIdx.x >> 6, lane = threadIdx.x & 63;
  int e0 = lane << 3;
  const float* zp = z + l * DIMV + e0;
  float x0[8];
  *(float4*)&x0[0] = *(const float4*)zp;
  *(float4*)&x0[4] = *(const float4*)(zp + 4);
  int d0 = c * 32 + wave * 8;
  float rf[8][8];
#pragma unroll
  for (int k = 0; k < 8; ++k) {
    const float* rp = Wq + (size_t)(d0 + k) * DIMV + e0;
    *(float4*)&rf[k][0] = *(const float4*)rp;
    *(float4*)&rf[k][4] = *(const float4*)(rp + 4);
  }
#pragma unroll
  for (int k = 0; k < 8; ++k) {
    float p = 0.f;
#pragma unroll
    for (int j = 0; j < 8; ++j) p = fmaf(rf[k][j], x0[j], p);
    p = wave_sum(p);
    if (lane == k) q[l * DIMV + d0 + k] = p;
  }
  if (wave == 0) {
    int n = c;
    int nvalid = (n == 15) ? 32 : 64;
    bool v = lane < nvalid;
    float cx = 0.f, cy = 0.f;
    if (v) {
      const float* cp = coords + ((size_t)(l * SEG + n * 32 + lane)) * 2;
      cx = cp[0]; cy = cp[1];
    }
    float inv = 1.0f / (float)nvalid;
    float mx = wave_sum(cx) * inv;
    float my = wave_sum(cy) * inv;
    if (lane == 0) {
      cmean[(l * NWIN + n) * 2]     = mx;
      cmean[(l * NWIN + n) * 2 + 1] = my;
    }
  }
}

// qk[l][e] = sum_d q[l][d]*Wk[d][e]; qw2 likewise on w2; qb2[l] = q_l . b2.
__global__ __launch_bounds__(256) void k_qproj(const float* __restrict__ q,
    const float* __restrict__ Wk, const float* __restrict__ w2,
    const float* __restrict__ b2, float* __restrict__ qk,
    float* __restrict__ qw2, float* __restrict__ qb2)
{
  int l = blockIdx.x >> 3, ec = blockIdx.x & 7;
  int wave = threadIdx.x >> 6, lane = threadIdx.x & 63;
  int t = threadIdx.x;
  __shared__ float qs[DIMV];
  __shared__ float pk[4][64], pw[4][64];
  qs[t] = q[l * DIMV + t];
  qs[t + 256] = q[l * DIMV + t + 256];
  __syncthreads();
  int e = ec * 64 + lane;
  int d0 = wave * 128;
  float ak = 0.f, aw = 0.f;
#pragma unroll 8
  for (int dd = 0; dd < 128; ++dd) {
    int d = d0 + dd;
    float qd = qs[d];
    ak = fmaf(qd, Wk[(size_t)d * DIMV + e], ak);
    aw = fmaf(qd, w2[(size_t)d * DIMV + e], aw);
  }
  pk[wave][lane] = ak;
  pw[wave][lane] = aw;
  __syncthreads();
  if (wave == 0) {
    qk[l * DIMV + e] = pk[0][lane] + pk[1][lane] + pk[2][lane] + pk[3][lane];
  } else if (wave == 1) {
    qw2[l * DIMV + e] = pw[0][lane] + pw[1][lane] + pw[2][lane] + pw[3][lane];
  } else if (wave == 2 && ec == 0) {
    int e0 = lane << 3;
    float pb = 0.f;
#pragma unroll
    for (int j = 0; j < 8; ++j) pb = fmaf(qs[e0 + j], b2[e0 + j], pb);
    pb = wave_sum(pb);
    if (lane == 0) qb2[l] = pb;
  }
}

// pos[l][n][w] = sum_d relu(dx*w1[d,0] + dy*w1[d,1] + b1[d]) * qw2[l][d]
// 256 blocks x 256 thr: wave per (l,n) window, lane = w.  Pure VALU, L1-hot params.
__global__ __launch_bounds__(256) void k_pos(const float* __restrict__ coords,
    const float* __restrict__ cmean, const float* __restrict__ qw2,
    const float* __restrict__ w1, const float* __restrict__ b1,
    float* __restrict__ pos)
{
  int widx = blockIdx.x * 4 + (threadIdx.x >> 6);   // 0..1023
  int lane = threadIdx.x & 63;
  int l = widx >> 4, n = widx & 15;
  int off = n * 32 + lane;
  int row = (off < SEG) ? off : SEG - 1;            // clamped gather (masked later)
  const float* cp = coords + ((size_t)(l * SEG + row)) * 2;
  float cx = cp[0], cy = cp[1];
  float mx = cmean[(l * NWIN + n) * 2], my = cmean[(l * NWIN + n) * 2 + 1];
  float dx = cx - mx, dy = cy - my;
  const float* qwp = qw2 + l * DIMV;
  float acc = 0.f;
#pragma unroll 8
  for (int d = 0; d < DIMV; ++d) {
    float2 wv = *(const float2*)(w1 + 2 * d);
    float h = fmaf(dx, wv.x, fmaf(dy, wv.y, b1[d]));
    acc = fmaf(fmaxf(h, 0.f), qwp[d], acc);
  }
  pos[(size_t)widx * WSZ + lane] = acc;
}

// One block per 96-row tile (l, c): rows [64c, 64c+96), which fully contains
// windows 2c and 2c+1.  512 thr = 8 waves x 12 rows; tile resident in
// rf[12][8] (96 VGPR) -- launch_bounds(512,1) gives the 256-VGPR cap so the
// pin cannot spill (round-7 failure).  Feats read ONCE for both windows.
__global__ __launch_bounds__(512, 1) void k_attn(
    const float* __restrict__ feats, const float* __restrict__ qk,
    const float* __restrict__ qb2, const float* __restrict__ pos,
    float* __restrict__ upart)
{
  int bid = blockIdx.x;                     // 512 blocks
  int swz = (bid & 7) * 64 + (bid >> 3);    // XCD chunking
  int l = swz >> 3, c = swz & 7;
  int wave = threadIdx.x >> 6, lane = threadIdx.x & 63;
  int e0 = lane << 3, t = threadIdx.x;
  int rows = SEG - 64 * c; if (rows > 96) rows = 96;   // 96, or 64 at c=7

  __shared__ float dts[96];
  __shared__ float attA[WSZ], attB[WSZ];
  __shared__ float upacc[8][DIMV];

  const float* fbase = feats + ((size_t)(l * SEG + c * 64)) * DIMV;

  // Stage the tile into registers (24 independent dwordx4 per thread).
  float rf[12][8];
#pragma unroll
  for (int k = 0; k < 12; ++k) {
    int r = wave * 12 + k;
    if (r < rows) {
      const float* rp = fbase + (size_t)r * DIMV + e0;
      *(float4*)&rf[k][0] = *(const float4*)rp;
      *(float4*)&rf[k][4] = *(const float4*)(rp + 4);
    } else {
#pragma unroll
      for (int j = 0; j < 8; ++j) rf[k][j] = 0.f;
    }
  }
  float qk8[8];
  {
    const float* p = qk + l * DIMV + e0;
    *(float4*)&qk8[0] = *(const float4*)p;
    *(float4*)&qk8[4] = *(const float4*)(p + 4);
  }
  float qb2l = qb2[l];

  // Pin the tile into VGPRs (no sinking / remat across barriers).
#pragma unroll
  for (int k = 0; k < 12; ++k)
#pragma unroll
    for (int j = 0; j < 8; ++j)
      asm volatile("" : "+v"(rf[k][j]));

  // Per-row dot with qk.
#pragma unroll
  for (int k = 0; k < 12; ++k) {
    int r = wave * 12 + k;
    float p = 0.f;
#pragma unroll
    for (int j = 0; j < 8; ++j) p = fmaf(qk8[j], rf[k][j], p);
    p = wave_sum(p);
    if (lane == k && r < rows) dts[r] = p;
  }
  __syncthreads();

  // Softmax of window 2c (wave 0: rows 0..63) and 2c+1 (wave 1: rows 32..95).
  const float* posA = pos + ((size_t)(l * NWIN) + 2 * c) * WSZ;
  const float* posB = posA + WSZ;
  if (wave == 0) {
    float lg = (dts[lane] + posA[lane] + qb2l) * INV_SQRT_D;
    float m = wave_max(lg);
    float ex = __expf(lg - m);
    float s = wave_sum(ex);
    attA[lane] = ex / s;
  } else if (wave == 1) {
    int r = 32 + lane;
    float lg = (r < rows) ? (dts[r] + posB[lane] + qb2l) * INV_SQRT_D : -1e9f;
    float m = wave_max(lg);
    float ex = __expf(lg - m);
    float s = wave_sum(ex);
    attB[lane] = ex / s;
  }
  __syncthreads();

  // Combined weighted sum for both windows from the RESIDENT tile.
  float u8[8];
#pragma unroll
  for (int j = 0; j < 8; ++j) u8[j] = 0.f;
#pragma unroll
  for (int k = 0; k < 12; ++k) {
    int r = wave * 12 + k;
    if (r < rows) {
      float g = 0.f;
      if (r < 64)  g += attA[r];
      if (r >= 32) g += attB[r - 32];
#pragma unroll
      for (int j = 0; j < 8; ++j) u8[j] = fmaf(g, rf[k][j], u8[j]);
    }
  }
  *(float4*)&upacc[wave][e0]     = *(float4*)&u8[0];
  *(float4*)&upacc[wave][e0 + 4] = *(float4*)&u8[4];
  __syncthreads();
  float a = 0.f;
#pragma unroll
  for (int wv = 0; wv < 8; ++wv) a += upacc[wv][t];
  upart[((size_t)(l * NB) + c) * DIMV + t] = a;
}

// tbuf[l][f] = (sum_c upart[l][c]) . Wv_f.  1024 blocks (inline reduction).
__global__ __launch_bounds__(256, 4) void k_uv(const float* __restrict__ upart,
    const float* __restrict__ Wv, float* __restrict__ tbuf)
{
  int l = blockIdx.x >> 4, c = blockIdx.x & 15;
  int wave = threadIdx.x >> 6, lane = threadIdx.x & 63;
  int e0 = lane << 3;
  float u8[8];
#pragma unroll
  for (int j = 0; j < 8; ++j) u8[j] = 0.f;
#pragma unroll
  for (int cc = 0; cc < NB; ++cc) {
    const float* up = upart + ((size_t)(l * NB) + cc) * DIMV + e0;
    float4 a = *(const float4*)up;
    float4 b = *(const float4*)(up + 4);
    u8[0] += a.x; u8[1] += a.y; u8[2] += a.z; u8[3] += a.w;
    u8[4] += b.x; u8[5] += b.y; u8[6] += b.z; u8[7] += b.w;
  }
  int f0 = c * 32 + wave * 8;
  float rf[8][8];
#pragma unroll
  for (int k = 0; k < 8; ++k) {
    const float* rp = Wv + (size_t)(f0 + k) * DIMV + e0;
    *(float4*)&rf[k][0] = *(const float4*)rp;
    *(float4*)&rf[k][4] = *(const float4*)(rp + 4);
  }
#pragma unroll
  for (int k = 0; k < 8; ++k) {
    float p = 0.f;
#pragma unroll
    for (int j = 0; j < 8; ++j) p = fmaf(rf[k][j], u8[j], p);
    p = wave_sum(p);
    if (lane == k) tbuf[l * DIMV + f0 + k] = p;
  }
}

// out[l][d] = tbuf_l . Wo_d + bo[d].  1024 blocks.
__global__ __launch_bounds__(256, 4) void k_out(const float* __restrict__ tbuf,
    const float* __restrict__ Wo, const float* __restrict__ bo,
    float* __restrict__ out)
{
  int l = blockIdx.x >> 4, c = blockIdx.x & 15;
  int wave = threadIdx.x >> 6, lane = threadIdx.x & 63;
  int e0 = lane << 3;
  const float* tp = tbuf + l * DIMV + e0;
  float x0[8];
  *(float4*)&x0[0] = *(const float4*)tp;
  *(float4*)&x0[4] = *(const float4*)(tp + 4);
  int d0 = c * 32 + wave * 8;
  float rf[8][8];
#pragma unroll
  for (int k = 0; k < 8; ++k) {
    const float* rp = Wo + (size_t)(d0 + k) * DIMV + e0;
    *(float4*)&rf[k][0] = *(const float4*)rp;
    *(float4*)&rf[k][4] = *(const float4*)(rp + 4);
  }
#pragma unroll
  for (int k = 0; k < 8; ++k) {
    float p = 0.f;
#pragma unroll
    for (int j = 0; j < 8; ++j) p = fmaf(rf[k][j], x0[j], p);
    p = wave_sum(p);
    if (lane == k) out[l * DIMV + d0 + k] = p + bo[d0 + k];
  }
}

extern "C" void kernel_launch(void* const* d_in, const int* in_sizes, int n_in,
                              void* d_out, int out_size, void* d_ws, size_t ws_size,
                              hipStream_t stream) {
  (void)in_sizes; (void)n_in; (void)out_size; (void)ws_size;
  const float* feats  = (const float*)d_in[0];
  const float* coords = (const float*)d_in[1];
  // d_in[2] = mask (all-False) -> unused
  const float* z   = (const float*)d_in[3];
  const float* Wq  = (const float*)d_in[4];
  const float* Wk  = (const float*)d_in[5];
  const float* Wv  = (const float*)d_in[6];
  const float* w1  = (const float*)d_in[7];
  const float* b1  = (const float*)d_in[8];
  const float* w2  = (const float*)d_in[9];
  const float* b2  = (const float*)d_in[10];
  const float* Wo  = (const float*)d_in[11];
  const float* bo  = (const float*)d_in[12];
  float* out = (float*)d_out;

  float* q     = (float*)d_ws;                  // 64*512
  float* qk    = q     + LTOK * DIMV;           // 64*512
  float* qw2   = qk    + LTOK * DIMV;           // 64*512
  float* qb2   = qw2   + LTOK * DIMV;           // 64
  float* cmean = qb2   + LTOK;                  // 64*16*2
  float* pos   = cmean + LTOK * NWIN * 2;       // 64*16*64
  float* tbuf  = pos   + LTOK * NWIN * WSZ;     // 64*512
  float* upart = tbuf  + LTOK * DIMV;           // 64*8*512   (~1.8 MB ws)

  hipLaunchKernelGGL(k_q,     dim3(LTOK * NWIN), dim3(256), 0, stream,
                     z, Wq, coords, q, cmean);
  hipLaunchKernelGGL(k_qproj, dim3(LTOK * 8),    dim3(256), 0, stream,
                     q, Wk, w2, b2, qk, qw2, qb2);
  hipLaunchKernelGGL(k_pos,   dim3(LTOK * NWIN / 4), dim3(256), 0, stream,
                     coords, cmean, qw2, w1, b1, pos);
  hipLaunchKernelGGL(k_attn,  dim3(LTOK * NB),   dim3(512), 0, stream,
                     feats, qk, qb2, pos, upart);
  hipLaunchKernelGGL(k_uv,    dim3(LTOK * NWIN), dim3(256), 0, stream,
                     upart, Wv, tbuf);
  hipLaunchKernelGGL(k_out,   dim3(LTOK * NWIN), dim3(256), 0, stream,
                     tbuf, Wo, bo, out);
}

// Round 10
// 72.156 us; speedup vs baseline: 1.0837x; 1.0837x over previous
//
#include <hip/hip_runtime.h>
#include <math.h>

#define DIMV 512
#define LTOK 64
#define SEG  512      // N_PATCH / L_TOK
#define NWIN 16
#define WSZ  64
#define INV_SQRT_D 0.044194173824159216f   // 1/sqrt(512)

__device__ __forceinline__ float wave_sum(float v) {
#pragma unroll
  for (int m = 1; m < 64; m <<= 1) v += __shfl_xor(v, m, 64);
  return v;
}
__device__ __forceinline__ float wave_max(float v) {
#pragma unroll
  for (int m = 1; m < 64; m <<= 1) v = fmaxf(v, __shfl_xor(v, m, 64));
  return v;
}

// q[l][d] = z_l . Wq_d (1024 blocks: 64 l x 16 chunks; 256 thr).
// Side task: wave 0 computes window (l, c)'s coordinate mean.
__global__ __launch_bounds__(256, 4) void k_q(const float* __restrict__ z,
    const float* __restrict__ Wq, const float* __restrict__ coords,
    float* __restrict__ q, float* __restrict__ cmean)
{
  int l = blockIdx.x >> 4, c = blockIdx.x & 15;
  int wave = threadIdx.x >> 6, lane = threadIdx.x & 63;
  int e0 = lane << 3;
  const float* zp = z + l * DIMV + e0;
  float x0[8];
  *(float4*)&x0[0] = *(const float4*)zp;
  *(float4*)&x0[4] = *(const float4*)(zp + 4);
  int d0 = c * 32 + wave * 8;
  float rf[8][8];
#pragma unroll
  for (int k = 0; k < 8; ++k) {
    const float* rp = Wq + (size_t)(d0 + k) * DIMV + e0;
    *(float4*)&rf[k][0] = *(const float4*)rp;
    *(float4*)&rf[k][4] = *(const float4*)(rp + 4);
  }
#pragma unroll
  for (int k = 0; k < 8; ++k) {
    float p = 0.f;
#pragma unroll
    for (int j = 0; j < 8; ++j) p = fmaf(rf[k][j], x0[j], p);
    p = wave_sum(p);
    if (lane == k) q[l * DIMV + d0 + k] = p;
  }
  if (wave == 0) {
    int n = c;
    int nvalid = (n == 15) ? 32 : 64;
    bool v = lane < nvalid;
    float cx = 0.f, cy = 0.f;
    if (v) {
      const float* cp = coords + ((size_t)(l * SEG + n * 32 + lane)) * 2;
      cx = cp[0]; cy = cp[1];
    }
    float inv = 1.0f / (float)nvalid;
    float mx = wave_sum(cx) * inv;
    float my = wave_sum(cy) * inv;
    if (lane == 0) {
      cmean[(l * NWIN + n) * 2]     = mx;
      cmean[(l * NWIN + n) * 2 + 1] = my;
    }
  }
}

// qk[l][e] = sum_d q[l][d]*Wk[d][e]; qw2 likewise on w2; qb2[l] = q_l . b2.
__global__ __launch_bounds__(256) void k_qproj(const float* __restrict__ q,
    const float* __restrict__ Wk, const float* __restrict__ w2,
    const float* __restrict__ b2, float* __restrict__ qk,
    float* __restrict__ qw2, float* __restrict__ qb2)
{
  int l = blockIdx.x >> 3, ec = blockIdx.x & 7;
  int wave = threadIdx.x >> 6, lane = threadIdx.x & 63;
  int t = threadIdx.x;
  __shared__ float qs[DIMV];
  __shared__ float pk[4][64], pw[4][64];
  qs[t] = q[l * DIMV + t];
  qs[t + 256] = q[l * DIMV + t + 256];
  __syncthreads();
  int e = ec * 64 + lane;
  int d0 = wave * 128;
  float ak = 0.f, aw = 0.f;
#pragma unroll 8
  for (int dd = 0; dd < 128; ++dd) {
    int d = d0 + dd;
    float qd = qs[d];
    ak = fmaf(qd, Wk[(size_t)d * DIMV + e], ak);
    aw = fmaf(qd, w2[(size_t)d * DIMV + e], aw);
  }
  pk[wave][lane] = ak;
  pw[wave][lane] = aw;
  __syncthreads();
  if (wave == 0) {
    qk[l * DIMV + e] = pk[0][lane] + pk[1][lane] + pk[2][lane] + pk[3][lane];
  } else if (wave == 1) {
    qw2[l * DIMV + e] = pw[0][lane] + pw[1][lane] + pw[2][lane] + pw[3][lane];
  } else if (wave == 2 && ec == 0) {
    int e0 = lane << 3;
    float pb = 0.f;
#pragma unroll
    for (int j = 0; j < 8; ++j) pb = fmaf(qs[e0 + j], b2[e0 + j], pb);
    pb = wave_sum(pb);
    if (lane == 0) qb2[l] = pb;
  }
}

// PASS 1: dts[l*SEG+r] = qk_l . feats_r.  Pure streaming: 1 fma/elem + one
// wave_sum per row.  1024 blocks x 256 thr (4 blk/CU = one full-GPU round
// over 64 MB), no barriers, nothing live across phases.
__global__ __launch_bounds__(256, 4) void k_dot(
    const float* __restrict__ feats, const float* __restrict__ qk,
    float* __restrict__ dts)
{
  int l = blockIdx.x >> 4, c = blockIdx.x & 15;
  int wave = threadIdx.x >> 6, lane = threadIdx.x & 63;
  int e0 = lane << 3;
  float qk8[8];
  {
    const float* p = qk + l * DIMV + e0;
    *(float4*)&qk8[0] = *(const float4*)p;
    *(float4*)&qk8[4] = *(const float4*)(p + 4);
  }
  int rbase = c * 32 + wave * 8;
  const float* fbase = feats + ((size_t)(l * SEG + rbase)) * DIMV;
  float rf[8][8];
#pragma unroll
  for (int k = 0; k < 8; ++k) {
    const float* rp = fbase + (size_t)k * DIMV + e0;
    *(float4*)&rf[k][0] = *(const float4*)rp;
    *(float4*)&rf[k][4] = *(const float4*)(rp + 4);
  }
#pragma unroll
  for (int k = 0; k < 8; ++k) {
    float p = 0.f;
#pragma unroll
    for (int j = 0; j < 8; ++j) p = fmaf(qk8[j], rf[k][j], p);
    p = wave_sum(p);
    if (lane == k) dts[l * SEG + rbase + k] = p;
  }
}

// Softmax per window, pos-MLP from LDS-staged params.
// 256 blocks x 256 thr; wave = one window; all 4 windows of a block share l.
__global__ __launch_bounds__(256) void k_soft(
    const float* __restrict__ coords, const float* __restrict__ cmean,
    const float* __restrict__ dts,   const float* __restrict__ qw2,
    const float* __restrict__ qb2,   const float* __restrict__ w1,
    const float* __restrict__ b1,    float* __restrict__ attn)
{
  int wave = threadIdx.x >> 6, lane = threadIdx.x & 63;
  int t = threadIdx.x;
  int widx0 = blockIdx.x * 4;
  int l = widx0 >> 4;                       // same l for all 4 waves
  __shared__ float qws[DIMV], b1s[DIMV], w1s[2 * DIMV];
#pragma unroll
  for (int i = 0; i < 2; ++i) {
    qws[t + 256 * i] = qw2[l * DIMV + t + 256 * i];
    b1s[t + 256 * i] = b1[t + 256 * i];
  }
#pragma unroll
  for (int i = 0; i < 4; ++i) w1s[t + 256 * i] = w1[t + 256 * i];
  __syncthreads();

  int widx = widx0 + wave;
  int n = widx & 15;
  int nvalid = (n == 15) ? 32 : 64;
  bool v = lane < nvalid;
  int off = n * 32 + lane;
  int row = v ? off : (SEG - 1);
  const float* cp = coords + ((size_t)(l * SEG + row)) * 2;
  float dx = cp[0] - cmean[(l * NWIN + n) * 2];
  float dy = cp[1] - cmean[(l * NWIN + n) * 2 + 1];
  float pos = 0.f;
#pragma unroll 8
  for (int d = 0; d < DIMV; ++d) {
    float h = fmaf(dx, w1s[2 * d], fmaf(dy, w1s[2 * d + 1], b1s[d]));
    pos = fmaf(fmaxf(h, 0.f), qws[d], pos);
  }
  float lg = v ? (dts[l * SEG + off] + pos + qb2[l]) * INV_SQRT_D : -1e9f;
  float m = wave_max(lg);
  float ex = __expf(lg - m);                // invalid lanes -> 0
  float s = wave_sum(ex);
  attn[(size_t)widx * WSZ + lane] = ex / s;
}

// PASS 2: upart[l][c][e] = sum_{j<32} g[j] * feats[32c+j][e], where
// g[j] = attn[c][j] + attn[c-1][32+j].  Combined weight read ONCE into LDS,
// then pure streaming fma.  1024 blocks x 256 thr, one full-GPU round;
// feats is L3-resident after pass 1.
__global__ __launch_bounds__(256, 4) void k_wsum(
    const float* __restrict__ feats, const float* __restrict__ attn,
    float* __restrict__ upart)
{
  int l = blockIdx.x >> 4, c = blockIdx.x & 15;
  int wave = threadIdx.x >> 6, lane = threadIdx.x & 63;
  int e0 = lane << 3, t = threadIdx.x;
  __shared__ float gs[32];
  __shared__ float upacc[4][DIMV];
  if (t < 32) {
    float g = attn[((size_t)(l * NWIN) + c) * WSZ + t];
    if (c > 0) g += attn[((size_t)(l * NWIN) + c - 1) * WSZ + 32 + t];
    gs[t] = g;
  }
  __syncthreads();
  int rbase = wave * 8;
  const float* fbase = feats + ((size_t)(l * SEG + c * 32 + rbase)) * DIMV;
  float u8[8];
#pragma unroll
  for (int j = 0; j < 8; ++j) u8[j] = 0.f;
#pragma unroll
  for (int k = 0; k < 8; ++k) {
    float g = gs[rbase + k];
    const float* rp = fbase + (size_t)k * DIMV + e0;
    float f8[8];
    *(float4*)&f8[0] = *(const float4*)rp;
    *(float4*)&f8[4] = *(const float4*)(rp + 4);
#pragma unroll
    for (int j = 0; j < 8; ++j) u8[j] = fmaf(g, f8[j], u8[j]);
  }
  *(float4*)&upacc[wave][e0]     = *(float4*)&u8[0];
  *(float4*)&upacc[wave][e0 + 4] = *(float4*)&u8[4];
  __syncthreads();
#pragma unroll
  for (int i = 0; i < 2; ++i) {
    int e = t + 256 * i;
    upart[((size_t)(l * NWIN) + c) * DIMV + e] =
        upacc[0][e] + upacc[1][e] + upacc[2][e] + upacc[3][e];
  }
}

// tbuf[l][f] = (sum_c upart[l][c]) . Wv_f.  1024 blocks (inline reduction).
__global__ __launch_bounds__(256, 4) void k_uv(const float* __restrict__ upart,
    const float* __restrict__ Wv, float* __restrict__ tbuf)
{
  int l = blockIdx.x >> 4, c = blockIdx.x & 15;
  int wave = threadIdx.x >> 6, lane = threadIdx.x & 63;
  int e0 = lane << 3;
  float u8[8];
#pragma unroll
  for (int j = 0; j < 8; ++j) u8[j] = 0.f;
#pragma unroll
  for (int cc = 0; cc < NWIN; ++cc) {
    const float* up = upart + ((size_t)(l * NWIN) + cc) * DIMV + e0;
    float4 a = *(const float4*)up;
    float4 b = *(const float4*)(up + 4);
    u8[0] += a.x; u8[1] += a.y; u8[2] += a.z; u8[3] += a.w;
    u8[4] += b.x; u8[5] += b.y; u8[6] += b.z; u8[7] += b.w;
  }
  int f0 = c * 32 + wave * 8;
  float rf[8][8];
#pragma unroll
  for (int k = 0; k < 8; ++k) {
    const float* rp = Wv + (size_t)(f0 + k) * DIMV + e0;
    *(float4*)&rf[k][0] = *(const float4*)rp;
    *(float4*)&rf[k][4] = *(const float4*)(rp + 4);
  }
#pragma unroll
  for (int k = 0; k < 8; ++k) {
    float p = 0.f;
#pragma unroll
    for (int j = 0; j < 8; ++j) p = fmaf(rf[k][j], u8[j], p);
    p = wave_sum(p);
    if (lane == k) tbuf[l * DIMV + f0 + k] = p;
  }
}

// out[l][d] = tbuf_l . Wo_d + bo[d].  1024 blocks.
__global__ __launch_bounds__(256, 4) void k_out(const float* __restrict__ tbuf,
    const float* __restrict__ Wo, const float* __restrict__ bo,
    float* __restrict__ out)
{
  int l = blockIdx.x >> 4, c = blockIdx.x & 15;
  int wave = threadIdx.x >> 6, lane = threadIdx.x & 63;
  int e0 = lane << 3;
  const float* tp = tbuf + l * DIMV + e0;
  float x0[8];
  *(float4*)&x0[0] = *(const float4*)tp;
  *(float4*)&x0[4] = *(const float4*)(tp + 4);
  int d0 = c * 32 + wave * 8;
  float rf[8][8];
#pragma unroll
  for (int k = 0; k < 8; ++k) {
    const float* rp = Wo + (size_t)(d0 + k) * DIMV + e0;
    *(float4*)&rf[k][0] = *(const float4*)rp;
    *(float4*)&rf[k][4] = *(const float4*)(rp + 4);
  }
#pragma unroll
  for (int k = 0; k < 8; ++k) {
    float p = 0.f;
#pragma unroll
    for (int j = 0; j < 8; ++j) p = fmaf(rf[k][j], x0[j], p);
    p = wave_sum(p);
    if (lane == k) out[l * DIMV + d0 + k] = p + bo[d0 + k];
  }
}

extern "C" void kernel_launch(void* const* d_in, const int* in_sizes, int n_in,
                              void* d_out, int out_size, void* d_ws, size_t ws_size,
                              hipStream_t stream) {
  (void)in_sizes; (void)n_in; (void)out_size; (void)ws_size;
  const float* feats  = (const float*)d_in[0];
  const float* coords = (const float*)d_in[1];
  // d_in[2] = mask (all-False) -> unused
  const float* z   = (const float*)d_in[3];
  const float* Wq  = (const float*)d_in[4];
  const float* Wk  = (const float*)d_in[5];
  const float* Wv  = (const float*)d_in[6];
  const float* w1  = (const float*)d_in[7];
  const float* b1  = (const float*)d_in[8];
  const float* w2  = (const float*)d_in[9];
  const float* b2  = (const float*)d_in[10];
  const float* Wo  = (const float*)d_in[11];
  const float* bo  = (const float*)d_in[12];
  float* out = (float*)d_out;

  float* q     = (float*)d_ws;                  // 64*512
  float* qk    = q     + LTOK * DIMV;           // 64*512
  float* qw2   = qk    + LTOK * DIMV;           // 64*512
  float* qb2   = qw2   + LTOK * DIMV;           // 64
  float* cmean = qb2   + LTOK;                  // 64*16*2
  float* dts   = cmean + LTOK * NWIN * 2;       // 64*512
  float* attn  = dts   + LTOK * SEG;            // 64*16*64
  float* tbuf  = attn  + LTOK * NWIN * WSZ;     // 64*512
  float* upart = tbuf  + LTOK * DIMV;           // 64*16*512  (~2.8 MB ws)

  hipLaunchKernelGGL(k_q,     dim3(LTOK * NWIN),     dim3(256), 0, stream,
                     z, Wq, coords, q, cmean);
  hipLaunchKernelGGL(k_qproj, dim3(LTOK * 8),        dim3(256), 0, stream,
                     q, Wk, w2, b2, qk, qw2, qb2);
  hipLaunchKernelGGL(k_dot,   dim3(LTOK * NWIN),     dim3(256), 0, stream,
                     feats, qk, dts);
  hipLaunchKernelGGL(k_soft,  dim3(LTOK * NWIN / 4), dim3(256), 0, stream,
                     coords, cmean, dts, qw2, qb2, w1, b1, attn);
  hipLaunchKernelGGL(k_wsum,  dim3(LTOK * NWIN),     dim3(256), 0, stream,
                     feats, attn, upart);
  hipLaunchKernelGGL(k_uv,    dim3(LTOK * NWIN),     dim3(256), 0, stream,
                     upart, Wv, tbuf);
  hipLaunchKernelGGL(k_out,   dim3(LTOK * NWIN),     dim3(256), 0, stream,
                     tbuf, Wo, bo, out);
}

// Round 11
// 68.657 us; speedup vs baseline: 1.1389x; 1.0510x over previous
//
#include <hip/hip_runtime.h>
#include <math.h>

#define DIMV 512
#define LTOK 64
#define SEG  512      // N_PATCH / L_TOK
#define NWIN 16
#define WSZ  64
#define INV_SQRT_D 0.044194173824159216f   // 1/sqrt(512)

__device__ __forceinline__ float wave_sum(float v) {
#pragma unroll
  for (int m = 1; m < 64; m <<= 1) v += __shfl_xor(v, m, 64);
  return v;
}
__device__ __forceinline__ float wave_max(float v) {
#pragma unroll
  for (int m = 1; m < 64; m <<= 1) v = fmaxf(v, __shfl_xor(v, m, 64));
  return v;
}

// q[l][d] = z_l . Wq_d (1024 blocks: 64 l x 16 chunks; 256 thr).
// Side task: wave 0 computes window (l, c)'s coordinate mean.
__global__ __launch_bounds__(256, 4) void k_q(const float* __restrict__ z,
    const float* __restrict__ Wq, const float* __restrict__ coords,
    float* __restrict__ q, float* __restrict__ cmean)
{
  int l = blockIdx.x >> 4, c = blockIdx.x & 15;
  int wave = threadIdx.x >> 6, lane = threadIdx.x & 63;
  int e0 = lane << 3;
  const float* zp = z + l * DIMV + e0;
  float x0[8];
  *(float4*)&x0[0] = *(const float4*)zp;
  *(float4*)&x0[4] = *(const float4*)(zp + 4);
  int d0 = c * 32 + wave * 8;
  float rf[8][8];
#pragma unroll
  for (int k = 0; k < 8; ++k) {
    const float* rp = Wq + (size_t)(d0 + k) * DIMV + e0;
    *(float4*)&rf[k][0] = *(const float4*)rp;
    *(float4*)&rf[k][4] = *(const float4*)(rp + 4);
  }
#pragma unroll
  for (int k = 0; k < 8; ++k) {
    float p = 0.f;
#pragma unroll
    for (int j = 0; j < 8; ++j) p = fmaf(rf[k][j], x0[j], p);
    p = wave_sum(p);
    if (lane == k) q[l * DIMV + d0 + k] = p;
  }
  if (wave == 0) {
    int n = c;
    int nvalid = (n == 15) ? 32 : 64;
    bool v = lane < nvalid;
    float cx = 0.f, cy = 0.f;
    if (v) {
      const float* cp = coords + ((size_t)(l * SEG + n * 32 + lane)) * 2;
      cx = cp[0]; cy = cp[1];
    }
    float inv = 1.0f / (float)nvalid;
    float mx = wave_sum(cx) * inv;
    float my = wave_sum(cy) * inv;
    if (lane == 0) {
      cmean[(l * NWIN + n) * 2]     = mx;
      cmean[(l * NWIN + n) * 2 + 1] = my;
    }
  }
}

// qk[l][e] = sum_d q[l][d]*Wk[d][e]; qw2 likewise on w2; qb2[l] = q_l . b2.
__global__ __launch_bounds__(256) void k_qproj(const float* __restrict__ q,
    const float* __restrict__ Wk, const float* __restrict__ w2,
    const float* __restrict__ b2, float* __restrict__ qk,
    float* __restrict__ qw2, float* __restrict__ qb2)
{
  int l = blockIdx.x >> 3, ec = blockIdx.x & 7;
  int wave = threadIdx.x >> 6, lane = threadIdx.x & 63;
  int t = threadIdx.x;
  __shared__ float qs[DIMV];
  __shared__ float pk[4][64], pw[4][64];
  qs[t] = q[l * DIMV + t];
  qs[t + 256] = q[l * DIMV + t + 256];
  __syncthreads();
  int e = ec * 64 + lane;
  int d0 = wave * 128;
  float ak = 0.f, aw = 0.f;
#pragma unroll 8
  for (int dd = 0; dd < 128; ++dd) {
    int d = d0 + dd;
    float qd = qs[d];
    ak = fmaf(qd, Wk[(size_t)d * DIMV + e], ak);
    aw = fmaf(qd, w2[(size_t)d * DIMV + e], aw);
  }
  pk[wave][lane] = ak;
  pw[wave][lane] = aw;
  __syncthreads();
  if (wave == 0) {
    qk[l * DIMV + e] = pk[0][lane] + pk[1][lane] + pk[2][lane] + pk[3][lane];
  } else if (wave == 1) {
    qw2[l * DIMV + e] = pw[0][lane] + pw[1][lane] + pw[2][lane] + pw[3][lane];
  } else if (wave == 2 && ec == 0) {
    int e0 = lane << 3;
    float pb = 0.f;
#pragma unroll
    for (int j = 0; j < 8; ++j) pb = fmaf(qs[e0 + j], b2[e0 + j], pb);
    pb = wave_sum(pb);
    if (lane == 0) qb2[l] = pb;
  }
}

// PASS 1: dts[l*SEG+r] = qk_l . feats_r.
// 2048 blocks x 256 thr, launch_bounds(256,8): 8 blocks/CU = 32 waves/CU
// (VGPR ~50 <= 64 cap).  Wave owns 4 rows; ~10 dwordx4 in flight per wave
// -> ~256 KB in flight per CU, far above the latency-BW product.
__global__ __launch_bounds__(256, 8) void k_dot(
    const float* __restrict__ feats, const float* __restrict__ qk,
    float* __restrict__ dts)
{
  int l = blockIdx.x >> 5, c = blockIdx.x & 31;
  int wave = threadIdx.x >> 6, lane = threadIdx.x & 63;
  int e0 = lane << 3;
  int rbase = c * 16 + wave * 4;
  const float* fbase = feats + ((size_t)(l * SEG + rbase)) * DIMV;
  float rf[4][8];
#pragma unroll
  for (int k = 0; k < 4; ++k) {
    const float* rp = fbase + (size_t)k * DIMV + e0;
    *(float4*)&rf[k][0] = *(const float4*)rp;
    *(float4*)&rf[k][4] = *(const float4*)(rp + 4);
  }
  float qk8[8];
  {
    const float* p = qk + l * DIMV + e0;
    *(float4*)&qk8[0] = *(const float4*)p;
    *(float4*)&qk8[4] = *(const float4*)(p + 4);
  }
#pragma unroll
  for (int k = 0; k < 4; ++k) {
    float s = 0.f;
#pragma unroll
    for (int j = 0; j < 8; ++j) s = fmaf(qk8[j], rf[k][j], s);
    s = wave_sum(s);
    if (lane == k) dts[l * SEG + rbase + k] = s;
  }
}

// Softmax per window; pos-MLP parallelized 4x: 1024 blocks x 256 thr,
// thread = (position p, d-quarter qd); serial chain is 128 not 512.
__global__ __launch_bounds__(256, 4) void k_soft(
    const float* __restrict__ coords, const float* __restrict__ cmean,
    const float* __restrict__ dts,   const float* __restrict__ qw2,
    const float* __restrict__ qb2,   const float* __restrict__ w1,
    const float* __restrict__ b1,    float* __restrict__ attn)
{
  int widx = blockIdx.x;                    // 0..1023
  int l = widx >> 4, n = widx & 15;
  int t = threadIdx.x;
  int p = t & 63, qd = t >> 6;
  __shared__ float w1s[2 * DIMV], b1s[DIMV], qws[DIMV], part[4][WSZ];
#pragma unroll
  for (int i = 0; i < 4; ++i) w1s[t + 256 * i] = w1[t + 256 * i];
#pragma unroll
  for (int i = 0; i < 2; ++i) {
    b1s[t + 256 * i] = b1[t + 256 * i];
    qws[t + 256 * i] = qw2[l * DIMV + t + 256 * i];
  }
  __syncthreads();
  int nvalid = (n == 15) ? 32 : 64;
  int off = n * 32 + p;
  int row = (p < nvalid) ? off : (SEG - 1);
  float dx = coords[((size_t)(l * SEG + row)) * 2]     - cmean[(l * NWIN + n) * 2];
  float dy = coords[((size_t)(l * SEG + row)) * 2 + 1] - cmean[(l * NWIN + n) * 2 + 1];
  float acc = 0.f;
  int d0 = qd * 128;
#pragma unroll 4
  for (int dd = 0; dd < 128; ++dd) {
    int d = d0 + dd;
    float h = fmaf(dx, w1s[2 * d], fmaf(dy, w1s[2 * d + 1], b1s[d]));
    acc = fmaf(fmaxf(h, 0.f), qws[d], acc);
  }
  part[qd][p] = acc;
  __syncthreads();
  if (t < 64) {
    float pos = part[0][p] + part[1][p] + part[2][p] + part[3][p];
    float lg = (p < nvalid) ? (dts[l * SEG + off] + pos + qb2[l]) * INV_SQRT_D
                            : -1e9f;
    float m = wave_max(lg);
    float ex = __expf(lg - m);
    float s = wave_sum(ex);
    attn[(size_t)widx * WSZ + p] = ex / s;
  }
}

// PASS 2: upart[l][c][e] = sum_{j<32} g[j] * feats[32c+j][e],
// g[j] = attn[c][j] + attn[c-1][32+j].  launch_bounds(256,8): 8 blocks/CU.
__global__ __launch_bounds__(256, 8) void k_wsum(
    const float* __restrict__ feats, const float* __restrict__ attn,
    float* __restrict__ upart)
{
  int l = blockIdx.x >> 4, c = blockIdx.x & 15;
  int wave = threadIdx.x >> 6, lane = threadIdx.x & 63;
  int e0 = lane << 3, t = threadIdx.x;
  __shared__ float gs[32];
  __shared__ float upacc[4][DIMV];
  if (t < 32) {
    float g = attn[((size_t)(l * NWIN) + c) * WSZ + t];
    if (c > 0) g += attn[((size_t)(l * NWIN) + c - 1) * WSZ + 32 + t];
    gs[t] = g;
  }
  __syncthreads();
  int rbase = wave * 8;
  const float* fbase = feats + ((size_t)(l * SEG + c * 32 + rbase)) * DIMV;
  float u8[8];
#pragma unroll
  for (int j = 0; j < 8; ++j) u8[j] = 0.f;
#pragma unroll
  for (int k = 0; k < 8; ++k) {
    float g = gs[rbase + k];
    const float* rp = fbase + (size_t)k * DIMV + e0;
    float f8[8];
    *(float4*)&f8[0] = *(const float4*)rp;
    *(float4*)&f8[4] = *(const float4*)(rp + 4);
#pragma unroll
    for (int j = 0; j < 8; ++j) u8[j] = fmaf(g, f8[j], u8[j]);
  }
  *(float4*)&upacc[wave][e0]     = *(float4*)&u8[0];
  *(float4*)&upacc[wave][e0 + 4] = *(float4*)&u8[4];
  __syncthreads();
#pragma unroll
  for (int i = 0; i < 2; ++i) {
    int e = t + 256 * i;
    upart[((size_t)(l * NWIN) + c) * DIMV + e] =
        upacc[0][e] + upacc[1][e] + upacc[2][e] + upacc[3][e];
  }
}

// tbuf[l][f] = (sum_c upart[l][c]) . Wv_f.  1024 blocks.
__global__ __launch_bounds__(256, 4) void k_uv(const float* __restrict__ upart,
    const float* __restrict__ Wv, float* __restrict__ tbuf)
{
  int l = blockIdx.x >> 4, c = blockIdx.x & 15;
  int wave = threadIdx.x >> 6, lane = threadIdx.x & 63;
  int e0 = lane << 3;
  float u8[8];
#pragma unroll
  for (int j = 0; j < 8; ++j) u8[j] = 0.f;
#pragma unroll
  for (int cc = 0; cc < NWIN; ++cc) {
    const float* up = upart + ((size_t)(l * NWIN) + cc) * DIMV + e0;
    float4 a = *(const float4*)up;
    float4 b = *(const float4*)(up + 4);
    u8[0] += a.x; u8[1] += a.y; u8[2] += a.z; u8[3] += a.w;
    u8[4] += b.x; u8[5] += b.y; u8[6] += b.z; u8[7] += b.w;
  }
  int f0 = c * 32 + wave * 8;
  float rf[8][8];
#pragma unroll
  for (int k = 0; k < 8; ++k) {
    const float* rp = Wv + (size_t)(f0 + k) * DIMV + e0;
    *(float4*)&rf[k][0] = *(const float4*)rp;
    *(float4*)&rf[k][4] = *(const float4*)(rp + 4);
  }
#pragma unroll
  for (int k = 0; k < 8; ++k) {
    float p = 0.f;
#pragma unroll
    for (int j = 0; j < 8; ++j) p = fmaf(rf[k][j], u8[j], p);
    p = wave_sum(p);
    if (lane == k) tbuf[l * DIMV + f0 + k] = p;
  }
}

// out[l][d] = tbuf_l . Wo_d + bo[d].  1024 blocks.
__global__ __launch_bounds__(256, 4) void k_out(const float* __restrict__ tbuf,
    const float* __restrict__ Wo, const float* __restrict__ bo,
    float* __restrict__ out)
{
  int l = blockIdx.x >> 4, c = blockIdx.x & 15;
  int wave = threadIdx.x >> 6, lane = threadIdx.x & 63;
  int e0 = lane << 3;
  const float* tp = tbuf + l * DIMV + e0;
  float x0[8];
  *(float4*)&x0[0] = *(const float4*)tp;
  *(float4*)&x0[4] = *(const float4*)(tp + 4);
  int d0 = c * 32 + wave * 8;
  float rf[8][8];
#pragma unroll
  for (int k = 0; k < 8; ++k) {
    const float* rp = Wo + (size_t)(d0 + k) * DIMV + e0;
    *(float4*)&rf[k][0] = *(const float4*)rp;
    *(float4*)&rf[k][4] = *(const float4*)(rp + 4);
  }
#pragma unroll
  for (int k = 0; k < 8; ++k) {
    float p = 0.f;
#pragma unroll
    for (int j = 0; j < 8; ++j) p = fmaf(rf[k][j], x0[j], p);
    p = wave_sum(p);
    if (lane == k) out[l * DIMV + d0 + k] = p + bo[d0 + k];
  }
}

extern "C" void kernel_launch(void* const* d_in, const int* in_sizes, int n_in,
                              void* d_out, int out_size, void* d_ws, size_t ws_size,
                              hipStream_t stream) {
  (void)in_sizes; (void)n_in; (void)out_size; (void)ws_size;
  const float* feats  = (const float*)d_in[0];
  const float* coords = (const float*)d_in[1];
  // d_in[2] = mask (all-False) -> unused
  const float* z   = (const float*)d_in[3];
  const float* Wq  = (const float*)d_in[4];
  const float* Wk  = (const float*)d_in[5];
  const float* Wv  = (const float*)d_in[6];
  const float* w1  = (const float*)d_in[7];
  const float* b1  = (const float*)d_in[8];
  const float* w2  = (const float*)d_in[9];
  const float* b2  = (const float*)d_in[10];
  const float* Wo  = (const float*)d_in[11];
  const float* bo  = (const float*)d_in[12];
  float* out = (float*)d_out;

  float* q     = (float*)d_ws;                  // 64*512
  float* qk    = q     + LTOK * DIMV;           // 64*512
  float* qw2   = qk    + LTOK * DIMV;           // 64*512
  float* qb2   = qw2   + LTOK * DIMV;           // 64
  float* cmean = qb2   + LTOK;                  // 64*16*2
  float* dts   = cmean + LTOK * NWIN * 2;       // 64*512
  float* attn  = dts   + LTOK * SEG;            // 64*16*64
  float* tbuf  = attn  + LTOK * NWIN * WSZ;     // 64*512
  float* upart = tbuf  + LTOK * DIMV;           // 64*16*512  (~2.8 MB ws)

  hipLaunchKernelGGL(k_q,     dim3(LTOK * NWIN),  dim3(256), 0, stream,
                     z, Wq, coords, q, cmean);
  hipLaunchKernelGGL(k_qproj, dim3(LTOK * 8),     dim3(256), 0, stream,
                     q, Wk, w2, b2, qk, qw2, qb2);
  hipLaunchKernelGGL(k_dot,   dim3(LTOK * 32),    dim3(256), 0, stream,
                     feats, qk, dts);
  hipLaunchKernelGGL(k_soft,  dim3(LTOK * NWIN),  dim3(256), 0, stream,
                     coords, cmean, dts, qw2, qb2, w1, b1, attn);
  hipLaunchKernelGGL(k_wsum,  dim3(LTOK * NWIN),  dim3(256), 0, stream,
                     feats, attn, upart);
  hipLaunchKernelGGL(k_uv,    dim3(LTOK * NWIN),  dim3(256), 0, stream,
                     upart, Wv, tbuf);
  hipLaunchKernelGGL(k_out,   dim3(LTOK * NWIN),  dim3(256), 0, stream,
                     tbuf, Wo, bo, out);
}